// Round 12
// baseline (223.625 us; speedup 1.0000x reference)
//
#include <hip/hip_runtime.h>

#define B_ 4
#define L_ 1024
#define DIM_ 1024
#define H_ 8
#define D_ 32
#define LSEG 32
#define NSEG (L_/LSEG)   // 32

typedef __bf16 bf16_t;
typedef __bf16 bf16x8 __attribute__((ext_vector_type(8)));
typedef float f32x4 __attribute__((ext_vector_type(4)));

__device__ __forceinline__ void gload_lds16(const bf16_t* g, bf16_t* l) {
  __builtin_amdgcn_global_load_lds((const __attribute__((address_space(1))) void*)g,
                                   (__attribute__((address_space(3))) void*)l, 16, 0, 0);
}
__device__ __forceinline__ void gload_lds16f(const float* g, float* l) {
  __builtin_amdgcn_global_load_lds((const __attribute__((address_space(1))) void*)g,
                                   (__attribute__((address_space(3))) void*)l, 16, 0, 0);
}

// ---------------- merged f32 -> bf16 converts (5 regions, 1 launch) --------
__global__ __launch_bounds__(256) void cvt_all(const float* __restrict__ x,
                                               const float* __restrict__ w1,
                                               const float* __restrict__ w2,
                                               const float* __restrict__ w3,
                                               const float* __restrict__ w4,
                                               bf16_t* __restrict__ ox,
                                               bf16_t* __restrict__ o1,
                                               bf16_t* __restrict__ o2,
                                               bf16_t* __restrict__ o3,
                                               bf16_t* __restrict__ o4) {
  int g = blockIdx.x;
  const float* in; bf16_t* out; int i;
  if      (g < 4096) { in = x;  out = ox; i = g * 256 + threadIdx.x; }
  else if (g < 5120) { in = w1; out = o1; i = (g - 4096) * 256 + threadIdx.x; }
  else if (g < 7168) { in = w2; out = o2; i = (g - 5120) * 256 + threadIdx.x; }
  else if (g < 7680) { in = w3; out = o3; i = (g - 7168) * 256 + threadIdx.x; }
  else               { in = w4; out = o4; i = (g - 7680) * 256 + threadIdx.x; }
  float4 v = ((const float4*)in)[i];
  union { bf16_t b[4]; unsigned long long q; } pk;
  pk.b[0] = (bf16_t)v.x; pk.b[1] = (bf16_t)v.y;
  pk.b[2] = (bf16_t)v.z; pk.b[3] = (bf16_t)v.w;
  ((unsigned long long*)out)[i] = pk.q;
}

// ---------------- NT GEMM, BM=128 BN={64,128} BK=64 (GEMM2) ----------------
// BN=64 grid(32,32): 1024 blocks = 4/CU -- measured ~34us faster than BN=128
// (2/CU, 73.5us) for the N=2048 GEMM2 (r4..r7 ledger). 16 MFMA/barrier-pair.
template<int BN, int ACT, int OUTBF, int GATE>
__global__ __launch_bounds__(256) void gemm_nt(const bf16_t* __restrict__ A,
                                               const bf16_t* __restrict__ Bm,
                                               const float* __restrict__ bias,
                                               void* __restrict__ Cout,
                                               int M, int N, int K) {
  constexpr int NI = BN / 32;
  constexpr int ISS_B = BN / 32;
  __shared__ __align__(16) bf16_t As[128 * 64];
  __shared__ __align__(16) bf16_t Bs[BN * 64];
  const int t = threadIdx.x;
  const int wid = t >> 6, lane = t & 63;
  const int wr = wid >> 1, wc = wid & 1;
  const int lr = lane & 15, lq = lane >> 4;
  const int bm = blockIdx.x, bn = blockIdx.y;
  const int rA = wid * 32 + (lane >> 3);
  const int rB = wid * (BN / 4) + (lane >> 3);
  const int c8 = (((lane & 7) ^ ((lane >> 3) & 7))) * 8;
  const bf16_t* Ag = A + (size_t)(bm * 128 + rA) * K + c8;
  const bf16_t* Bg = Bm + (size_t)(bn * BN + rB) * K + c8;
  bf16_t* AsW = As + (wid * 32) * 64;
  bf16_t* BsW = Bs + (wid * (BN / 4)) * 64;
  f32x4 acc[4][NI] = {};
  for (int k0 = 0; k0 < K; k0 += 64) {
#pragma unroll
    for (int j = 0; j < 4; ++j)
      gload_lds16(Ag + (size_t)j * 8 * K, AsW + j * 8 * 64);
#pragma unroll
    for (int j = 0; j < ISS_B; ++j)
      gload_lds16(Bg + (size_t)j * 8 * K, BsW + j * 8 * 64);
    Ag += 64; Bg += 64;
    __syncthreads();
#pragma unroll
    for (int ks = 0; ks < 2; ++ks) {
      const int sg = ks * 4 + lq;
      const int sl = (sg ^ (lr & 7)) * 8;
      bf16x8 af[4], bfv[NI];
#pragma unroll
      for (int mi = 0; mi < 4; ++mi)
        af[mi] = *(const bf16x8*)&As[(wr * 64 + mi * 16 + lr) * 64 + sl];
#pragma unroll
      for (int ni = 0; ni < NI; ++ni)
        bfv[ni] = *(const bf16x8*)&Bs[(wc * (BN/2) + ni * 16 + lr) * 64 + sl];
#pragma unroll
      for (int mi = 0; mi < 4; ++mi)
#pragma unroll
        for (int ni = 0; ni < NI; ++ni)
          acc[mi][ni] = __builtin_amdgcn_mfma_f32_16x16x32_bf16(af[mi], bfv[ni], acc[mi][ni], 0, 0, 0);
    }
    __syncthreads();
  }
#pragma unroll
  for (int mi = 0; mi < 4; ++mi) {
#pragma unroll
    for (int ni = 0; ni < NI; ++ni) {
      int colg = bn * BN + wc * (BN/2) + ni * 16 + lr;
      float bb = bias[colg];
#pragma unroll
      for (int r = 0; r < 4; ++r) {
        int rowg = bm * 128 + wr * 64 + mi * 16 + lq * 4 + r;
        float v = acc[mi][ni][r] + bb;
        if (ACT == 1) v = v / (1.0f + __expf(-v));
        if (GATE) {
          float wv = __shfl_xor(v, 1);
          if ((colg & 7) >= 6) {
            float m2 = v * v + wv * wv;
            v *= sqrtf(m2) / (1.0f + m2);
          }
        }
        if (OUTBF) ((bf16_t*)Cout)[(size_t)rowg * N + colg] = (bf16_t)v;
        else       ((float*)Cout)[(size_t)rowg * N + colg] = v;
      }
    }
  }
}

// ---------------- NT GEMM, 512 thr, BM=128 BN=64 BK=128 (GEMM1/3/4) --------
// Waves-per-block occupancy fix: same tile/LDS/swizzle as gemm_nt64, covered
// by 8 waves (4Mx2N, 32x32 wave-tiles) instead of 4. Grid stays 512 blocks
// but resident threads double -> 16 waves/CU (was 8). Per-wave 16 MFMA per
// barrier-pair (GEMM2's proven density); block total unchanged (128).
template<int ACT, int OUTBF>
__global__ __launch_bounds__(512) void gemm_nt8w(const bf16_t* __restrict__ A,
                                                 const bf16_t* __restrict__ Bm,
                                                 const float* __restrict__ bias,
                                                 void* __restrict__ Cout,
                                                 int M, int N, int K) {
  __shared__ __align__(16) bf16_t As[128 * 128];   // 32 KB
  __shared__ __align__(16) bf16_t Bs[64 * 128];    // 16 KB
  const int t = threadIdx.x;
  const int wid = t >> 6, lane = t & 63;
  const int wr = wid >> 1, wc = wid & 1;           // 4 x 2 wave grid
  const int lr = lane & 15, lq = lane >> 4;
  const int bm = blockIdx.x, bn = blockIdx.y;
  const int crow = t >> 4;                         // staging row 0..31
  const int c8 = ((t & 15) ^ (crow & 15)) * 8;     // swizzled global col
  const bf16_t* Ag = A + (size_t)(bm * 128 + crow) * K + c8;
  const bf16_t* Bg = Bm + (size_t)(bn * 64 + crow) * K + c8;
  bf16_t* AsW = As + (wid * 4) * 128;              // + lane*8 implicit in HW
  bf16_t* BsW = Bs + (wid * 4) * 128;
  f32x4 acc[2][2] = {};
  for (int k0 = 0; k0 < K; k0 += 128) {
#pragma unroll
    for (int j = 0; j < 4; ++j)                    // A: 4 x 32 rows
      gload_lds16(Ag + (size_t)j * 32 * K, AsW + j * 32 * 128);
#pragma unroll
    for (int j = 0; j < 2; ++j)                    // B: 2 x 32 rows
      gload_lds16(Bg + (size_t)j * 32 * K, BsW + j * 32 * 128);
    Ag += 128; Bg += 128;
    __syncthreads();
#pragma unroll
    for (int ks = 0; ks < 4; ++ks) {
      const int sg = ks * 4 + lq;
      const int sl = (sg ^ lr) * 8;
      bf16x8 af[2], bfv[2];
#pragma unroll
      for (int mi = 0; mi < 2; ++mi)
        af[mi] = *(const bf16x8*)&As[(wr * 32 + mi * 16 + lr) * 128 + sl];
#pragma unroll
      for (int ni = 0; ni < 2; ++ni)
        bfv[ni] = *(const bf16x8*)&Bs[(wc * 32 + ni * 16 + lr) * 128 + sl];
#pragma unroll
      for (int mi = 0; mi < 2; ++mi)
#pragma unroll
        for (int ni = 0; ni < 2; ++ni)
          acc[mi][ni] = __builtin_amdgcn_mfma_f32_16x16x32_bf16(af[mi], bfv[ni], acc[mi][ni], 0, 0, 0);
    }
    __syncthreads();
  }
#pragma unroll
  for (int mi = 0; mi < 2; ++mi) {
#pragma unroll
    for (int ni = 0; ni < 2; ++ni) {
      int colg = bn * 64 + wc * 32 + ni * 16 + lr;
      float bb = bias[colg];
#pragma unroll
      for (int r = 0; r < 4; ++r) {
        int rowg = bm * 128 + wr * 32 + mi * 16 + lq * 4 + r;
        float v = acc[mi][ni][r] + bb;
        if (ACT == 1) v = v / (1.0f + __expf(-v));
        if (OUTBF) ((bf16_t*)Cout)[(size_t)rowg * N + colg] = (bf16_t)v;
        else       ((float*)Cout)[(size_t)rowg * N + colg] = v;
      }
    }
  }
}

// ---------------- Pass 1: scan (LSEG=32), r8 version (best measured) -------
// Pipelined A/B register sets (LDS latency hidden under VALU) + wave-0-only
// P/qP (e-independent work skipped on waves 1-3). r8 ~40us vs r7-plain 42.4
// vs r9-parallel-prefix 47.5.
__global__ __launch_bounds__(256) void scan_seg(const float* __restrict__ qkva,
                                                float* __restrict__ y_loc,
                                                float* __restrict__ qP,
                                                float* __restrict__ Aseg,
                                                float* __restrict__ Hfin) {
  __shared__ __align__(16) float Q[LSEG * 256];    // 32 KB
  const int t = threadIdx.x;
  const int seg = blockIdx.x;              // [0, 1024)
  const int s = seg & (NSEG - 1);
  const int bh = seg >> 5;                 // NSEG==32
  const int h = bh & (H_ - 1), b = bh >> 3;
  const int wid = t >> 6, lane = t & 63;
  const int dg = lane & 7, eh = lane >> 3;
  const int e = wid * 8 + eh;
  const float* gb = qkva + ((size_t)(b * L_ + s * LSEG) * H_ + h) * 256;
#pragma unroll
  for (int j = 0; j < 8; ++j) {
    const int l = wid * 8 + j;             // wave-uniform row index
    gload_lds16f(gb + (size_t)l * (H_ * 256) + lane * 4, Q + l * 256);
  }
  __syncthreads();
  float hr[4] = {}, hi[4] = {};
  float Pr[4] = {1,1,1,1}, Pi[4] = {0,0,0,0};
  const size_t row0 = ((size_t)(b * L_ + s * LSEG) * H_ + h) * D_;

  float4 qkA[4], qkB[4];
  float2 aaA[4], aaB[4];
  float2 vvA, vvB;

  auto LOADR = [&](int l, float4 (&qk)[4], float2 (&aa)[4], float2& vv) {
    const float* R = Q + l * 256;
    vv = *(const float2*)(R + e * 8 + 4);
#pragma unroll
    for (int j = 0; j < 4; ++j) {
      qk[j] = *(const float4*)(R + (dg + 8 * j) * 8);
      aa[j] = *(const float2*)(R + (dg + 8 * j) * 8 + 6);
    }
  };

  auto STEP = [&](int l, float4 (&qk)[4], float2 (&aa)[4], float2& vv) {
    const size_t rowl = row0 + (size_t)l * (H_ * D_);
    float ytr = 0.f, yti = 0.f;
    if (wid == 0) {                        // wave-uniform: only wave 0 pays
      float2 qpv[4];
#pragma unroll
      for (int j = 0; j < 4; ++j) {
        float nPr = aa[j].x * Pr[j] - aa[j].y * Pi[j];
        float nPi = aa[j].x * Pi[j] + aa[j].y * Pr[j];
        Pr[j] = nPr; Pi[j] = nPi;
        qpv[j].x = qk[j].x * nPr - qk[j].y * nPi;
        qpv[j].y = qk[j].x * nPi + qk[j].y * nPr;
      }
      if (lane < 8) {
#pragma unroll
        for (int j = 0; j < 4; ++j)
          *(float2*)(qP + (rowl + dg + 8 * j) * 2) = qpv[j];
      }
    }
#pragma unroll
    for (int j = 0; j < 4; ++j) {
      float kvr = qk[j].z * vv.x - qk[j].w * vv.y;
      float kvi = qk[j].z * vv.y + qk[j].w * vv.x;
      float nhr = aa[j].x * hr[j] - aa[j].y * hi[j] + kvr;
      float nhi = aa[j].x * hi[j] + aa[j].y * hr[j] + kvi;
      hr[j] = nhr; hi[j] = nhi;
      ytr += qk[j].x * nhr - qk[j].y * nhi;
      yti += qk[j].x * nhi + qk[j].y * nhr;
    }
    ytr += __shfl_down(ytr, 4); yti += __shfl_down(yti, 4);
    ytr += __shfl_down(ytr, 2); yti += __shfl_down(yti, 2);
    ytr += __shfl_down(ytr, 1); yti += __shfl_down(yti, 1);
    if (dg == 0)
      *(float2*)(y_loc + (rowl + e) * 2) = make_float2(ytr, yti);
  };

  LOADR(0, qkA, aaA, vvA);
  for (int l = 0; l < LSEG; l += 2) {
    LOADR(l + 1, qkB, aaB, vvB);
    STEP(l, qkA, aaA, vvA);
    LOADR(l + 2 < LSEG ? l + 2 : LSEG - 1, qkA, aaA, vvA);
    STEP(l + 1, qkB, aaB, vvB);
  }

  const size_t segb = (size_t)seg * D_;
  if (t < 8) {
#pragma unroll
    for (int j = 0; j < 4; ++j)
      *(float2*)(Aseg + (segb + dg + 8 * j) * 2) = make_float2(Pr[j], Pi[j]);
  }
#pragma unroll
  for (int j = 0; j < 4; ++j)
    *(float2*)(Hfin + ((segb + dg + 8 * j) * D_ + e) * 2) = make_float2(hr[j], hi[j]);
}

// ---------------- Pass 2: combine segments (NSEG=32), depth-8 prefetch -----
__global__ __launch_bounds__(128) void seg_combine(const float* __restrict__ h0re,
                                                   const float* __restrict__ h0im,
                                                   const float* __restrict__ Aseg,
                                                   const float* __restrict__ Hfin,
                                                   float* __restrict__ Hc) {
  const int bh = blockIdx.x >> 3;
  const int eg = blockIdx.x & 7;
  const int h = bh & (H_ - 1);
  const int t = threadIdx.x;
  const int d = t >> 2;
  const int e = eg * 4 + (t & 3);
  float cr = h0re[((size_t)h * D_ + d) * D_ + e];
  float ci = h0im[((size_t)h * D_ + d) * D_ + e];
  const size_t idx0  = ((size_t)bh * NSEG * D_ + d) * D_ + e;  // +s*D_*D_
  const size_t aidx0 = (size_t)bh * NSEG * D_ + d;             // +s*D_
  float2 Ab[8], Fb[8];
#pragma unroll
  for (int p = 0; p < 8; ++p) {
    Ab[p] = *(const float2*)(Aseg + (aidx0 + (size_t)p * D_) * 2);
    Fb[p] = *(const float2*)(Hfin + (idx0 + (size_t)p * D_ * D_) * 2);
  }
  for (int so = 0; so < NSEG; so += 8) {
#pragma unroll
    for (int p = 0; p < 8; ++p) {
      const int s = so + p;
      float2 A0 = Ab[p], F0 = Fb[p];
      if (so + 8 < NSEG) {
        Ab[p] = *(const float2*)(Aseg + (aidx0 + (size_t)(s + 8) * D_) * 2);
        Fb[p] = *(const float2*)(Hfin + (idx0 + (size_t)(s + 8) * D_ * D_) * 2);
      }
      *(float2*)(Hc + (idx0 + (size_t)s * D_ * D_) * 2) = make_float2(cr, ci);
      float nr = A0.x * cr - A0.y * ci + F0.x;
      float ni = A0.x * ci + A0.y * cr + F0.y;
      cr = nr; ci = ni;
    }
  }
}

// ---------------- Pass 3: y += qP @ Hcarry; emit y2 (bf16), LSEG=32 --------
__global__ __launch_bounds__(256) void y_correct(const float* __restrict__ y_loc,
                                                 const float* __restrict__ qP,
                                                 const float* __restrict__ Hc,
                                                 bf16_t* __restrict__ y2b) {
  __shared__ __align__(16) float Hs[D_ * D_ * 2];   // 8 KB
  const int seg = blockIdx.x;
  const int s = seg & (NSEG - 1);
  const int bh = seg >> 5;
  const int h = bh & (H_ - 1), b = bh >> 3;
  const int t = threadIdx.x;
  const float4* src = (const float4*)(Hc + (size_t)seg * (D_ * D_ * 2));
  ((float4*)Hs)[t] = src[t];
  ((float4*)Hs)[t + 256] = src[t + 256];
  __syncthreads();
  const int ep = (t & 15) * 2;     // 2 e per thread
#pragma unroll
  for (int half = 0; half < 2; ++half) {
    const int l = half * 16 + (t >> 4);    // 0..31
    const int lg = s * LSEG + l;
    const size_t rowc = ((size_t)(b * L_ + lg) * H_ + h) * D_;
    const float* qpr = qP + rowc * 2;
    float4 y0 = *(const float4*)(y_loc + (rowc + ep) * 2);
    float ac_r[2] = {y0.x, y0.z}, ac_i[2] = {y0.y, y0.w};
#pragma unroll 4
    for (int d = 0; d < D_; ++d) {
      float2 p = *(const float2*)(qpr + d * 2);
      float4 hv = *(const float4*)&Hs[(d * D_ + ep) * 2];
      ac_r[0] += p.x * hv.x - p.y * hv.y; ac_i[0] += p.x * hv.y + p.y * hv.x;
      ac_r[1] += p.x * hv.z - p.y * hv.w; ac_i[1] += p.x * hv.w + p.y * hv.z;
    }
    union { bf16_t bv[4]; uint2 q; } pk;
    pk.bv[0] = (bf16_t)ac_r[0]; pk.bv[1] = (bf16_t)ac_i[0];
    pk.bv[2] = (bf16_t)ac_r[1]; pk.bv[3] = (bf16_t)ac_i[1];
    *(uint2*)(y2b + (size_t)(b * L_ + lg) * (H_ * D_ * 2) + (h * D_ + ep) * 2) = pk.q;
  }
}

// ---------------- launcher ------------------------------------------------
extern "C" void kernel_launch(void* const* d_in, const int* in_sizes, int n_in,
                              void* d_out, int out_size, void* d_ws, size_t ws_size,
                              hipStream_t stream) {
  const float* x      = (const float*)d_in[0];
  const float* W_in   = (const float*)d_in[1];
  const float* b_in   = (const float*)d_in[2];
  const float* W_qkva = (const float*)d_in[3];
  const float* b_qkva = (const float*)d_in[4];
  const float* W_y    = (const float*)d_in[5];
  const float* b_y    = (const float*)d_in[6];
  const float* W_out  = (const float*)d_in[7];
  const float* b_out  = (const float*)d_in[8];
  const float* h0re   = (const float*)d_in[9];
  const float* h0im   = (const float*)d_in[10];

  char* w = (char*)d_ws;
  const size_t MB = 1ull << 20;
  bf16_t* Wb_in   = (bf16_t*)(w + 0*MB);    // 2 MB
  bf16_t* Wb_qkva = (bf16_t*)(w + 2*MB);    // 4 MB
  bf16_t* Wb_y    = (bf16_t*)(w + 6*MB);    // 1 MB
  bf16_t* Wb_out  = (bf16_t*)(w + 7*MB);    // 2 MB
  bf16_t* xb      = (bf16_t*)(w + 9*MB);    // 8 MB (dead after GEMM1)
  float*  qP      = (float*) (w + 9*MB);    // 8 MB (overlay xb)
  bf16_t* u       = (bf16_t*)(w + 17*MB);   // 8 MB (dead after GEMM2)
  float*  y_loc   = (float*) (w + 17*MB);   // 8 MB (overlay u)
  float*  qkva    = (float*) (w + 25*MB);   // 32 MB [b,l,h,d,c] (dead after scan)
  float*  Hc      = (float*) (w + 25*MB);   // 8 MB (overlay qkva)
  bf16_t* y2b     = (bf16_t*)(w + 41*MB);   // 4 MB (overlay qkva)
  bf16_t* z       = (bf16_t*)(w + 45*MB);   // 8 MB (overlay qkva)
  float*  Aseg    = (float*) (w + 57*MB);   // 0.25 MB
  float*  Hfin    = (float*) (w + 58*MB);   // 8 MB -> total 66 MB

  cvt_all<<<8704, 256, 0, stream>>>(x, W_in, W_qkva, W_y, W_out,
                                    xb, Wb_in, Wb_qkva, Wb_y, Wb_out);

  // GEMM1: u = silu(x @ W_in^T + b_in)           512 blocks x 512 thr (8 waves)
  gemm_nt8w<1,1><<<dim3(32, 16), 512, 0, stream>>>(xb, Wb_in, b_in, u, 4096, 1024, 1024);
  // GEMM2: qkva = gate(u @ W_qkva^T + b_qkva), f32   1024 blocks (4/CU), BN=64
  gemm_nt<64,0,0,1><<<dim3(32, 32), 256, 0, stream>>>(u, Wb_qkva, b_qkva, qkva, 4096, 2048, 1024);
  // recurrence (LSEG=32: 1024 segments)
  scan_seg   <<<1024, 256, 0, stream>>>(qkva, y_loc, qP, Aseg, Hfin);
  seg_combine<<<256,  128, 0, stream>>>(h0re, h0im, Aseg, Hfin, Hc);
  y_correct  <<<1024, 256, 0, stream>>>(y_loc, qP, Hc, y2b);
  // GEMM3: z = silu(y2 @ W_y^T + b_y)            512 blocks x 512 thr
  gemm_nt8w<1,1><<<dim3(32, 16), 512, 0, stream>>>(y2b, Wb_y, b_y, z, 4096, 1024, 512);
  // GEMM4: out = z @ W_out^T + b_out             512 blocks x 512 thr
  gemm_nt8w<0,0><<<dim3(32, 16), 512, 0, stream>>>(z, Wb_out, b_out, (float*)d_out, 4096, 1024, 1024);
}

// Round 13
// 218.462 us; speedup vs baseline: 1.0236x; 1.0236x over previous
//
#include <hip/hip_runtime.h>

#define B_ 4
#define L_ 1024
#define DIM_ 1024
#define H_ 8
#define D_ 32
#define LSEG 32
#define NSEG (L_/LSEG)   // 32

typedef __bf16 bf16_t;
typedef __bf16 bf16x8 __attribute__((ext_vector_type(8)));
typedef float f32x4 __attribute__((ext_vector_type(4)));

__device__ __forceinline__ void gload_lds16(const bf16_t* g, bf16_t* l) {
  __builtin_amdgcn_global_load_lds((const __attribute__((address_space(1))) void*)g,
                                   (__attribute__((address_space(3))) void*)l, 16, 0, 0);
}
__device__ __forceinline__ void gload_lds16f(const float* g, float* l) {
  __builtin_amdgcn_global_load_lds((const __attribute__((address_space(1))) void*)g,
                                   (__attribute__((address_space(3))) void*)l, 16, 0, 0);
}

// ---------------- merged f32 -> bf16 converts (5 regions, 1 launch) --------
__global__ __launch_bounds__(256) void cvt_all(const float* __restrict__ x,
                                               const float* __restrict__ w1,
                                               const float* __restrict__ w2,
                                               const float* __restrict__ w3,
                                               const float* __restrict__ w4,
                                               bf16_t* __restrict__ ox,
                                               bf16_t* __restrict__ o1,
                                               bf16_t* __restrict__ o2,
                                               bf16_t* __restrict__ o3,
                                               bf16_t* __restrict__ o4) {
  int g = blockIdx.x;
  const float* in; bf16_t* out; int i;
  if      (g < 4096) { in = x;  out = ox; i = g * 256 + threadIdx.x; }
  else if (g < 5120) { in = w1; out = o1; i = (g - 4096) * 256 + threadIdx.x; }
  else if (g < 7168) { in = w2; out = o2; i = (g - 5120) * 256 + threadIdx.x; }
  else if (g < 7680) { in = w3; out = o3; i = (g - 7168) * 256 + threadIdx.x; }
  else               { in = w4; out = o4; i = (g - 7680) * 256 + threadIdx.x; }
  float4 v = ((const float4*)in)[i];
  union { bf16_t b[4]; unsigned long long q; } pk;
  pk.b[0] = (bf16_t)v.x; pk.b[1] = (bf16_t)v.y;
  pk.b[2] = (bf16_t)v.z; pk.b[3] = (bf16_t)v.w;
  ((unsigned long long*)out)[i] = pk.q;
}

// ---------------- NT GEMM, BM=128 BN={64,128} BK=64 (GEMM2) ----------------
// BN=64 grid(32,32): 1024 blocks = 4/CU -- measured ~34us faster than BN=128
// (2/CU, 73.5us) for the N=2048 GEMM2 (r4..r7 ledger). 16 MFMA/barrier-pair.
template<int BN, int ACT, int OUTBF, int GATE>
__global__ __launch_bounds__(256) void gemm_nt(const bf16_t* __restrict__ A,
                                               const bf16_t* __restrict__ Bm,
                                               const float* __restrict__ bias,
                                               void* __restrict__ Cout,
                                               int M, int N, int K) {
  constexpr int NI = BN / 32;
  constexpr int ISS_B = BN / 32;
  __shared__ __align__(16) bf16_t As[128 * 64];
  __shared__ __align__(16) bf16_t Bs[BN * 64];
  const int t = threadIdx.x;
  const int wid = t >> 6, lane = t & 63;
  const int wr = wid >> 1, wc = wid & 1;
  const int lr = lane & 15, lq = lane >> 4;
  const int bm = blockIdx.x, bn = blockIdx.y;
  const int rA = wid * 32 + (lane >> 3);
  const int rB = wid * (BN / 4) + (lane >> 3);
  const int c8 = (((lane & 7) ^ ((lane >> 3) & 7))) * 8;
  const bf16_t* Ag = A + (size_t)(bm * 128 + rA) * K + c8;
  const bf16_t* Bg = Bm + (size_t)(bn * BN + rB) * K + c8;
  bf16_t* AsW = As + (wid * 32) * 64;
  bf16_t* BsW = Bs + (wid * (BN / 4)) * 64;
  f32x4 acc[4][NI] = {};
  for (int k0 = 0; k0 < K; k0 += 64) {
#pragma unroll
    for (int j = 0; j < 4; ++j)
      gload_lds16(Ag + (size_t)j * 8 * K, AsW + j * 8 * 64);
#pragma unroll
    for (int j = 0; j < ISS_B; ++j)
      gload_lds16(Bg + (size_t)j * 8 * K, BsW + j * 8 * 64);
    Ag += 64; Bg += 64;
    __syncthreads();
#pragma unroll
    for (int ks = 0; ks < 2; ++ks) {
      const int sg = ks * 4 + lq;
      const int sl = (sg ^ (lr & 7)) * 8;
      bf16x8 af[4], bfv[NI];
#pragma unroll
      for (int mi = 0; mi < 4; ++mi)
        af[mi] = *(const bf16x8*)&As[(wr * 64 + mi * 16 + lr) * 64 + sl];
#pragma unroll
      for (int ni = 0; ni < NI; ++ni)
        bfv[ni] = *(const bf16x8*)&Bs[(wc * (BN/2) + ni * 16 + lr) * 64 + sl];
#pragma unroll
      for (int mi = 0; mi < 4; ++mi)
#pragma unroll
        for (int ni = 0; ni < NI; ++ni)
          acc[mi][ni] = __builtin_amdgcn_mfma_f32_16x16x32_bf16(af[mi], bfv[ni], acc[mi][ni], 0, 0, 0);
    }
    __syncthreads();
  }
#pragma unroll
  for (int mi = 0; mi < 4; ++mi) {
#pragma unroll
    for (int ni = 0; ni < NI; ++ni) {
      int colg = bn * BN + wc * (BN/2) + ni * 16 + lr;
      float bb = bias[colg];
#pragma unroll
      for (int r = 0; r < 4; ++r) {
        int rowg = bm * 128 + wr * 64 + mi * 16 + lq * 4 + r;
        float v = acc[mi][ni][r] + bb;
        if (ACT == 1) v = v / (1.0f + __expf(-v));
        if (GATE) {
          float wv = __shfl_xor(v, 1);
          if ((colg & 7) >= 6) {
            float m2 = v * v + wv * wv;
            v *= sqrtf(m2) / (1.0f + m2);
          }
        }
        if (OUTBF) ((bf16_t*)Cout)[(size_t)rowg * N + colg] = (bf16_t)v;
        else       ((float*)Cout)[(size_t)rowg * N + colg] = v;
      }
    }
  }
}

// ---------------- NT GEMM, BM=128 BN=64 BK=128 (GEMM1/3/4) -----------------
// Best measured config for the N=1024 GEMMs (r6/r8/r10/r12 ledger): beats
// BK=64 (+13us), BM=64/BK=128 (+1.7us), split-K=2 (+9us), 8-wave (+1.6us),
// f32-A staging (+45us). Grid-capped at 512 blocks = 2/CU; structural.
template<int ACT, int OUTBF>
__global__ __launch_bounds__(256) void gemm_nt64(const bf16_t* __restrict__ A,
                                                 const bf16_t* __restrict__ Bm,
                                                 const float* __restrict__ bias,
                                                 void* __restrict__ Cout,
                                                 int M, int N, int K) {
  __shared__ __align__(16) bf16_t As[128 * 128];   // 32 KB
  __shared__ __align__(16) bf16_t Bs[64 * 128];    // 16 KB
  const int t = threadIdx.x;
  const int wid = t >> 6, lane = t & 63;
  const int wr = wid >> 1, wc = wid & 1;
  const int lr = lane & 15, lq = lane >> 4;
  const int bm = blockIdx.x, bn = blockIdx.y;
  const int crow = wid * 4 + (lane >> 4);          // staging row (mod 16)
  const int c8 = ((lane & 15) ^ crow) * 8;         // swizzled global col
  const bf16_t* Ag = A + (size_t)(bm * 128 + crow) * K + c8;
  const bf16_t* Bg = Bm + (size_t)(bn * 64 + crow) * K + c8;
  bf16_t* AsW = As + (wid * 4) * 128;
  bf16_t* BsW = Bs + (wid * 4) * 128;
  f32x4 acc[4][2] = {};
  for (int k0 = 0; k0 < K; k0 += 128) {
#pragma unroll
    for (int j = 0; j < 8; ++j)
      gload_lds16(Ag + (size_t)j * 16 * K, AsW + j * 16 * 128);
#pragma unroll
    for (int j = 0; j < 4; ++j)
      gload_lds16(Bg + (size_t)j * 16 * K, BsW + j * 16 * 128);
    Ag += 128; Bg += 128;
    __syncthreads();
#pragma unroll
    for (int ks = 0; ks < 4; ++ks) {
      const int sg = ks * 4 + lq;
      const int sl = (sg ^ lr) * 8;
      bf16x8 af[4], bfv[2];
#pragma unroll
      for (int mi = 0; mi < 4; ++mi)
        af[mi] = *(const bf16x8*)&As[(wr * 64 + mi * 16 + lr) * 128 + sl];
#pragma unroll
      for (int ni = 0; ni < 2; ++ni)
        bfv[ni] = *(const bf16x8*)&Bs[(wc * 32 + ni * 16 + lr) * 128 + sl];
#pragma unroll
      for (int mi = 0; mi < 4; ++mi)
#pragma unroll
        for (int ni = 0; ni < 2; ++ni)
          acc[mi][ni] = __builtin_amdgcn_mfma_f32_16x16x32_bf16(af[mi], bfv[ni], acc[mi][ni], 0, 0, 0);
    }
    __syncthreads();
  }
#pragma unroll
  for (int mi = 0; mi < 4; ++mi) {
#pragma unroll
    for (int ni = 0; ni < 2; ++ni) {
      int colg = bn * 64 + wc * 32 + ni * 16 + lr;
      float bb = bias[colg];
#pragma unroll
      for (int r = 0; r < 4; ++r) {
        int rowg = bm * 128 + wr * 64 + mi * 16 + lq * 4 + r;
        float v = acc[mi][ni][r] + bb;
        if (ACT == 1) v = v / (1.0f + __expf(-v));
        if (OUTBF) ((bf16_t*)Cout)[(size_t)rowg * N + colg] = (bf16_t)v;
        else       ((float*)Cout)[(size_t)rowg * N + colg] = v;
      }
    }
  }
}

// ---------------- Pass 1: scan (LSEG=32), r8 version (best measured) -------
// Pipelined A/B register sets (LDS latency hidden under VALU) + wave-0-only
// P/qP (e-independent work skipped on waves 1-3). r8 ~40us vs r7-plain 42.4
// vs r9-parallel-prefix 47.5.
__global__ __launch_bounds__(256) void scan_seg(const float* __restrict__ qkva,
                                                float* __restrict__ y_loc,
                                                float* __restrict__ qP,
                                                float* __restrict__ Aseg,
                                                float* __restrict__ Hfin) {
  __shared__ __align__(16) float Q[LSEG * 256];    // 32 KB
  const int t = threadIdx.x;
  const int seg = blockIdx.x;              // [0, 1024)
  const int s = seg & (NSEG - 1);
  const int bh = seg >> 5;                 // NSEG==32
  const int h = bh & (H_ - 1), b = bh >> 3;
  const int wid = t >> 6, lane = t & 63;
  const int dg = lane & 7, eh = lane >> 3;
  const int e = wid * 8 + eh;
  const float* gb = qkva + ((size_t)(b * L_ + s * LSEG) * H_ + h) * 256;
#pragma unroll
  for (int j = 0; j < 8; ++j) {
    const int l = wid * 8 + j;             // wave-uniform row index
    gload_lds16f(gb + (size_t)l * (H_ * 256) + lane * 4, Q + l * 256);
  }
  __syncthreads();
  float hr[4] = {}, hi[4] = {};
  float Pr[4] = {1,1,1,1}, Pi[4] = {0,0,0,0};
  const size_t row0 = ((size_t)(b * L_ + s * LSEG) * H_ + h) * D_;

  float4 qkA[4], qkB[4];
  float2 aaA[4], aaB[4];
  float2 vvA, vvB;

  auto LOADR = [&](int l, float4 (&qk)[4], float2 (&aa)[4], float2& vv) {
    const float* R = Q + l * 256;
    vv = *(const float2*)(R + e * 8 + 4);
#pragma unroll
    for (int j = 0; j < 4; ++j) {
      qk[j] = *(const float4*)(R + (dg + 8 * j) * 8);
      aa[j] = *(const float2*)(R + (dg + 8 * j) * 8 + 6);
    }
  };

  auto STEP = [&](int l, float4 (&qk)[4], float2 (&aa)[4], float2& vv) {
    const size_t rowl = row0 + (size_t)l * (H_ * D_);
    float ytr = 0.f, yti = 0.f;
    if (wid == 0) {                        // wave-uniform: only wave 0 pays
      float2 qpv[4];
#pragma unroll
      for (int j = 0; j < 4; ++j) {
        float nPr = aa[j].x * Pr[j] - aa[j].y * Pi[j];
        float nPi = aa[j].x * Pi[j] + aa[j].y * Pr[j];
        Pr[j] = nPr; Pi[j] = nPi;
        qpv[j].x = qk[j].x * nPr - qk[j].y * nPi;
        qpv[j].y = qk[j].x * nPi + qk[j].y * nPr;
      }
      if (lane < 8) {
#pragma unroll
        for (int j = 0; j < 4; ++j)
          *(float2*)(qP + (rowl + dg + 8 * j) * 2) = qpv[j];
      }
    }
#pragma unroll
    for (int j = 0; j < 4; ++j) {
      float kvr = qk[j].z * vv.x - qk[j].w * vv.y;
      float kvi = qk[j].z * vv.y + qk[j].w * vv.x;
      float nhr = aa[j].x * hr[j] - aa[j].y * hi[j] + kvr;
      float nhi = aa[j].x * hi[j] + aa[j].y * hr[j] + kvi;
      hr[j] = nhr; hi[j] = nhi;
      ytr += qk[j].x * nhr - qk[j].y * nhi;
      yti += qk[j].x * nhi + qk[j].y * nhr;
    }
    ytr += __shfl_down(ytr, 4); yti += __shfl_down(yti, 4);
    ytr += __shfl_down(ytr, 2); yti += __shfl_down(yti, 2);
    ytr += __shfl_down(ytr, 1); yti += __shfl_down(yti, 1);
    if (dg == 0)
      *(float2*)(y_loc + (rowl + e) * 2) = make_float2(ytr, yti);
  };

  LOADR(0, qkA, aaA, vvA);
  for (int l = 0; l < LSEG; l += 2) {
    LOADR(l + 1, qkB, aaB, vvB);
    STEP(l, qkA, aaA, vvA);
    LOADR(l + 2 < LSEG ? l + 2 : LSEG - 1, qkA, aaA, vvA);
    STEP(l + 1, qkB, aaB, vvB);
  }

  const size_t segb = (size_t)seg * D_;
  if (t < 8) {
#pragma unroll
    for (int j = 0; j < 4; ++j)
      *(float2*)(Aseg + (segb + dg + 8 * j) * 2) = make_float2(Pr[j], Pi[j]);
  }
#pragma unroll
  for (int j = 0; j < 4; ++j)
    *(float2*)(Hfin + ((segb + dg + 8 * j) * D_ + e) * 2) = make_float2(hr[j], hi[j]);
}

// ---------------- Pass 2: combine segments (NSEG=32), depth-8 prefetch -----
__global__ __launch_bounds__(128) void seg_combine(const float* __restrict__ h0re,
                                                   const float* __restrict__ h0im,
                                                   const float* __restrict__ Aseg,
                                                   const float* __restrict__ Hfin,
                                                   float* __restrict__ Hc) {
  const int bh = blockIdx.x >> 3;
  const int eg = blockIdx.x & 7;
  const int h = bh & (H_ - 1);
  const int t = threadIdx.x;
  const int d = t >> 2;
  const int e = eg * 4 + (t & 3);
  float cr = h0re[((size_t)h * D_ + d) * D_ + e];
  float ci = h0im[((size_t)h * D_ + d) * D_ + e];
  const size_t idx0  = ((size_t)bh * NSEG * D_ + d) * D_ + e;  // +s*D_*D_
  const size_t aidx0 = (size_t)bh * NSEG * D_ + d;             // +s*D_
  float2 Ab[8], Fb[8];
#pragma unroll
  for (int p = 0; p < 8; ++p) {
    Ab[p] = *(const float2*)(Aseg + (aidx0 + (size_t)p * D_) * 2);
    Fb[p] = *(const float2*)(Hfin + (idx0 + (size_t)p * D_ * D_) * 2);
  }
  for (int so = 0; so < NSEG; so += 8) {
#pragma unroll
    for (int p = 0; p < 8; ++p) {
      const int s = so + p;
      float2 A0 = Ab[p], F0 = Fb[p];
      if (so + 8 < NSEG) {
        Ab[p] = *(const float2*)(Aseg + (aidx0 + (size_t)(s + 8) * D_) * 2);
        Fb[p] = *(const float2*)(Hfin + (idx0 + (size_t)(s + 8) * D_ * D_) * 2);
      }
      *(float2*)(Hc + (idx0 + (size_t)s * D_ * D_) * 2) = make_float2(cr, ci);
      float nr = A0.x * cr - A0.y * ci + F0.x;
      float ni = A0.x * ci + A0.y * cr + F0.y;
      cr = nr; ci = ni;
    }
  }
}

// ---------------- Pass 3: y += qP @ Hcarry; emit y2 (bf16), LSEG=32 --------
__global__ __launch_bounds__(256) void y_correct(const float* __restrict__ y_loc,
                                                 const float* __restrict__ qP,
                                                 const float* __restrict__ Hc,
                                                 bf16_t* __restrict__ y2b) {
  __shared__ __align__(16) float Hs[D_ * D_ * 2];   // 8 KB
  const int seg = blockIdx.x;
  const int s = seg & (NSEG - 1);
  const int bh = seg >> 5;
  const int h = bh & (H_ - 1), b = bh >> 3;
  const int t = threadIdx.x;
  const float4* src = (const float4*)(Hc + (size_t)seg * (D_ * D_ * 2));
  ((float4*)Hs)[t] = src[t];
  ((float4*)Hs)[t + 256] = src[t + 256];
  __syncthreads();
  const int ep = (t & 15) * 2;     // 2 e per thread
#pragma unroll
  for (int half = 0; half < 2; ++half) {
    const int l = half * 16 + (t >> 4);    // 0..31
    const int lg = s * LSEG + l;
    const size_t rowc = ((size_t)(b * L_ + lg) * H_ + h) * D_;
    const float* qpr = qP + rowc * 2;
    float4 y0 = *(const float4*)(y_loc + (rowc + ep) * 2);
    float ac_r[2] = {y0.x, y0.z}, ac_i[2] = {y0.y, y0.w};
#pragma unroll 4
    for (int d = 0; d < D_; ++d) {
      float2 p = *(const float2*)(qpr + d * 2);
      float4 hv = *(const float4*)&Hs[(d * D_ + ep) * 2];
      ac_r[0] += p.x * hv.x - p.y * hv.y; ac_i[0] += p.x * hv.y + p.y * hv.x;
      ac_r[1] += p.x * hv.z - p.y * hv.w; ac_i[1] += p.x * hv.w + p.y * hv.z;
    }
    union { bf16_t bv[4]; uint2 q; } pk;
    pk.bv[0] = (bf16_t)ac_r[0]; pk.bv[1] = (bf16_t)ac_i[0];
    pk.bv[2] = (bf16_t)ac_r[1]; pk.bv[3] = (bf16_t)ac_i[1];
    *(uint2*)(y2b + (size_t)(b * L_ + lg) * (H_ * D_ * 2) + (h * D_ + ep) * 2) = pk.q;
  }
}

// ---------------- launcher ------------------------------------------------
extern "C" void kernel_launch(void* const* d_in, const int* in_sizes, int n_in,
                              void* d_out, int out_size, void* d_ws, size_t ws_size,
                              hipStream_t stream) {
  const float* x      = (const float*)d_in[0];
  const float* W_in   = (const float*)d_in[1];
  const float* b_in   = (const float*)d_in[2];
  const float* W_qkva = (const float*)d_in[3];
  const float* b_qkva = (const float*)d_in[4];
  const float* W_y    = (const float*)d_in[5];
  const float* b_y    = (const float*)d_in[6];
  const float* W_out  = (const float*)d_in[7];
  const float* b_out  = (const float*)d_in[8];
  const float* h0re   = (const float*)d_in[9];
  const float* h0im   = (const float*)d_in[10];

  char* w = (char*)d_ws;
  const size_t MB = 1ull << 20;
  bf16_t* Wb_in   = (bf16_t*)(w + 0*MB);    // 2 MB
  bf16_t* Wb_qkva = (bf16_t*)(w + 2*MB);    // 4 MB
  bf16_t* Wb_y    = (bf16_t*)(w + 6*MB);    // 1 MB
  bf16_t* Wb_out  = (bf16_t*)(w + 7*MB);    // 2 MB
  bf16_t* xb      = (bf16_t*)(w + 9*MB);    // 8 MB (dead after GEMM1)
  float*  qP      = (float*) (w + 9*MB);    // 8 MB (overlay xb)
  bf16_t* u       = (bf16_t*)(w + 17*MB);   // 8 MB (dead after GEMM2)
  float*  y_loc   = (float*) (w + 17*MB);   // 8 MB (overlay u)
  float*  qkva    = (float*) (w + 25*MB);   // 32 MB [b,l,h,d,c] (dead after scan)
  float*  Hc      = (float*) (w + 25*MB);   // 8 MB (overlay qkva)
  bf16_t* y2b     = (bf16_t*)(w + 41*MB);   // 4 MB (overlay qkva)
  bf16_t* z       = (bf16_t*)(w + 45*MB);   // 8 MB (overlay qkva)
  float*  Aseg    = (float*) (w + 57*MB);   // 0.25 MB
  float*  Hfin    = (float*) (w + 58*MB);   // 8 MB -> total 66 MB

  cvt_all<<<8704, 256, 0, stream>>>(x, W_in, W_qkva, W_y, W_out,
                                    xb, Wb_in, Wb_qkva, Wb_y, Wb_out);

  // GEMM1: u = silu(x @ W_in^T + b_in)               512 blocks, BK=128
  gemm_nt64<1,1><<<dim3(32, 16), 256, 0, stream>>>(xb, Wb_in, b_in, u, 4096, 1024, 1024);
  // GEMM2: qkva = gate(u @ W_qkva^T + b_qkva), f32   1024 blocks (4/CU), BN=64
  gemm_nt<64,0,0,1><<<dim3(32, 32), 256, 0, stream>>>(u, Wb_qkva, b_qkva, qkva, 4096, 2048, 1024);
  // recurrence (LSEG=32: 1024 segments)
  scan_seg   <<<1024, 256, 0, stream>>>(qkva, y_loc, qP, Aseg, Hfin);
  seg_combine<<<256,  128, 0, stream>>>(h0re, h0im, Aseg, Hfin, Hc);
  y_correct  <<<1024, 256, 0, stream>>>(y_loc, qP, Hc, y2b);
  // GEMM3: z = silu(y2 @ W_y^T + b_y)                512 blocks, BK=128
  gemm_nt64<1,1><<<dim3(32, 16), 256, 0, stream>>>(y2b, Wb_y, b_y, z, 4096, 1024, 512);
  // GEMM4: out = z @ W_out^T + b_out                 512 blocks, BK=128
  gemm_nt64<0,0><<<dim3(32, 16), 256, 0, stream>>>(z, Wb_out, b_out, (float*)d_out, 4096, 1024, 1024);
}